// Round 1
// baseline (1101.778 us; speedup 1.0000x reference)
//
#include <hip/hip_runtime.h>
#include <hip/hip_bf16.h>
#include <stdint.h>

// MaskedMHA decode: B=32, S=1, PAST=2048, H=32, KV=8, D=128, HIDDEN=4096
#define NHEAD 32
#define NKV 8
#define HDIM 128
#define HIDDEN_ 4096
#define QKVO 6144        // (8*2+32)*128
#define NB 32
#define PAST_ 2048
#define TT 2049
#define KDOFF 4096       // k_new offset within qkv row
#define VDOFF 5120       // v_new offset within qkv row

typedef __attribute__((ext_vector_type(8))) short bf16x8;
typedef __attribute__((ext_vector_type(4))) float f32x4;

__device__ inline short f2bf(float f) {
  uint32_t u = __float_as_uint(f);
  u = (u + 0x7fffu + ((u >> 16) & 1u)) >> 16;  // RNE
  return (short)u;
}

__device__ inline bf16x8 cvt8(float4 lo, float4 hi) {
  bf16x8 r;
  r[0] = f2bf(lo.x); r[1] = f2bf(lo.y); r[2] = f2bf(lo.z); r[3] = f2bf(lo.w);
  r[4] = f2bf(hi.x); r[5] = f2bf(hi.y); r[6] = f2bf(hi.z); r[7] = f2bf(hi.w);
  return r;
}

// ws is re-poisoned before every launch: init qkv = bias broadcast.
__global__ __launch_bounds__(256) void qkv_init_k(float* __restrict__ qkv,
                                                  const float* __restrict__ bias) {
  int i = blockIdx.x * 256 + threadIdx.x;
  qkv[i] = bias[i % QKVO];
}

// qkv[32,6144] += X[32,4096] @ W[6144,4096]^T  (bf16 MFMA, register-only, split-K atomics)
// grid (96 n-blocks of 64 cols, 8 k-slices of 512), 4 waves/block (16 cols each)
__global__ __launch_bounds__(256) void qkv_gemm_k(const float* __restrict__ X,
                                                  const float* __restrict__ W,
                                                  float* __restrict__ qkv) {
  const int wave = threadIdx.x >> 6;
  const int lane = threadIdx.x & 63;
  const int quad = lane >> 4;
  const int l16  = lane & 15;
  const int n    = blockIdx.x * 64 + wave * 16 + l16;   // output col (B-frag row of W)
  const int k0   = blockIdx.y * 512 + quad * 8;

  const float* xr0 = X + l16 * HIDDEN_;          // batches 0..15  (A-frag m = l16)
  const float* xr1 = X + (16 + l16) * HIDDEN_;   // batches 16..31
  const float* wr  = W + (size_t)n * HIDDEN_;

  f32x4 acc0 = {0.f, 0.f, 0.f, 0.f};
  f32x4 acc1 = {0.f, 0.f, 0.f, 0.f};
  for (int it = 0; it < 16; ++it) {
    int k = k0 + it * 32;
    const float4* pa0 = (const float4*)(xr0 + k);
    const float4* pa1 = (const float4*)(xr1 + k);
    const float4* pb  = (const float4*)(wr + k);
    bf16x8 a0 = cvt8(pa0[0], pa0[1]);
    bf16x8 a1 = cvt8(pa1[0], pa1[1]);
    bf16x8 b  = cvt8(pb[0],  pb[1]);
    acc0 = __builtin_amdgcn_mfma_f32_16x16x32_bf16(a0, b, acc0, 0, 0, 0);
    acc1 = __builtin_amdgcn_mfma_f32_16x16x32_bf16(a1, b, acc1, 0, 0, 0);
  }
  // C/D layout: col = lane&15 (n), row = quad*4 + reg (m = batch)
  #pragma unroll
  for (int r = 0; r < 4; ++r) {
    atomicAdd(&qkv[(size_t)(quad * 4 + r) * QKVO + n], acc0[r]);
    atomicAdd(&qkv[(size_t)(16 + quad * 4 + r) * QKVO + n], acc1[r]);
  }
}

// Fused: KV-cache concat (copy) + GQA decode attention.
// One block per (b, kvh); 4 waves = the 4 GQA heads of that kv group.
// Copy tile-by-tile so score/PV re-reads hit L2.
__global__ __launch_bounds__(256) void attn_k(const float* __restrict__ kc,
                                              const float* __restrict__ vc,
                                              const float* __restrict__ mask,
                                              const float* __restrict__ qkv,
                                              float* __restrict__ out,
                                              float* __restrict__ k_cat,
                                              float* __restrict__ v_cat) {
  const int b    = blockIdx.x >> 3;
  const int kvh  = blockIdx.x & 7;
  const int tid  = threadIdx.x;
  const int wave = tid >> 6;
  const int lane = tid & 63;
  const float scale = 0.08838834764831845f;  // 1/sqrt(128)

  __shared__ float q_lds[4][HDIM];
  __shared__ float sc[4][2052];

  // stage q for the 4 heads of this kv group
  for (int i = tid; i < 4 * HDIM; i += 256) {
    int hh = i >> 7, d = i & 127;
    q_lds[hh][d] = qkv[(size_t)b * QKVO + (kvh * 4 + hh) * HDIM + d];
  }
  // append new K/V row (t = 2048) to the concat outputs
  if (tid < HDIM) {
    k_cat[((size_t)(b * TT + PAST_) * NKV + kvh) * HDIM + tid] =
        qkv[(size_t)b * QKVO + KDOFF + kvh * HDIM + tid];
  } else {
    int d = tid - HDIM;
    v_cat[((size_t)(b * TT + PAST_) * NKV + kvh) * HDIM + d] =
        qkv[(size_t)b * QKVO + VDOFF + kvh * HDIM + d];
  }
  __syncthreads();

  const float4* qr = (const float4*)q_lds[wave];

  // ---- K: copy + scores, 16 tiles x 128 rows ----
  for (int tile = 0; tile < 16; ++tile) {
    #pragma unroll 4
    for (int i = tid; i < 4096; i += 256) {       // 128 rows * 32 float4
      int row = i >> 5, c = i & 31;
      int t = tile * 128 + row;
      float4 val = ((const float4*)kc)[((size_t)(b * PAST_ + t) * NKV + kvh) * 32 + c];
      ((float4*)k_cat)[((size_t)(b * TT + t) * NKV + kvh) * 32 + c] = val;
    }
    #pragma unroll
    for (int rep = 0; rep < 2; ++rep) {
      int t = tile * 128 + rep * 64 + lane;
      const float4* kr = (const float4*)(kc + ((size_t)(b * PAST_ + t) * NKV + kvh) * HDIM);
      float s = 0.f;
      #pragma unroll 8
      for (int d4 = 0; d4 < 32; ++d4) {
        float4 k4 = kr[d4]; float4 q4 = qr[d4];
        s += k4.x * q4.x + k4.y * q4.y + k4.z * q4.z + k4.w * q4.w;
      }
      sc[wave][t] = s * scale + mask[b * TT + t];
    }
  }
  // tail score t = 2048 (k_new straight from qkv; all lanes redundant, lane 0 writes)
  {
    const float4* kr = (const float4*)(qkv + (size_t)b * QKVO + KDOFF + kvh * HDIM);
    float s = 0.f;
    #pragma unroll 8
    for (int d4 = 0; d4 < 32; ++d4) {
      float4 k4 = kr[d4]; float4 q4 = qr[d4];
      s += k4.x * q4.x + k4.y * q4.y + k4.z * q4.z + k4.w * q4.w;
    }
    if (lane == 0) sc[wave][PAST_] = s * scale + mask[b * TT + PAST_];
  }
  __syncthreads();

  // ---- softmax per wave (head) ----
  float m = -1e30f;
  for (int t = lane; t < TT; t += 64) m = fmaxf(m, sc[wave][t]);
  #pragma unroll
  for (int off = 32; off > 0; off >>= 1) m = fmaxf(m, __shfl_xor(m, off));
  float l = 0.f;
  for (int t = lane; t < TT; t += 64) {
    float p = __expf(sc[wave][t] - m);
    sc[wave][t] = p;
    l += p;
  }
  #pragma unroll
  for (int off = 32; off > 0; off >>= 1) l += __shfl_xor(l, off);
  __syncthreads();

  // ---- V: copy + PV, 16 tiles x 128 rows; lanes over d (float2 each) ----
  float2 acc = {0.f, 0.f};
  for (int tile = 0; tile < 16; ++tile) {
    #pragma unroll 4
    for (int i = tid; i < 4096; i += 256) {
      int row = i >> 5, c = i & 31;
      int t = tile * 128 + row;
      float4 val = ((const float4*)vc)[((size_t)(b * PAST_ + t) * NKV + kvh) * 32 + c];
      ((float4*)v_cat)[((size_t)(b * TT + t) * NKV + kvh) * 32 + c] = val;
    }
    #pragma unroll 4
    for (int r = 0; r < 128; ++r) {
      int t = tile * 128 + r;
      float p = sc[wave][t];
      float2 v = ((const float2*)(vc + ((size_t)(b * PAST_ + t) * NKV + kvh) * HDIM))[lane];
      acc.x += p * v.x;
      acc.y += p * v.y;
    }
  }
  {  // tail t = 2048: v_new from qkv
    float p = sc[wave][PAST_];
    float2 v = ((const float2*)(qkv + (size_t)b * QKVO + VDOFF + kvh * HDIM))[lane];
    acc.x += p * v.x;
    acc.y += p * v.y;
  }
  float inv = 1.0f / l;
  int h = kvh * 4 + wave;
  float2 o; o.x = acc.x * inv; o.y = acc.y * inv;
  ((float2*)(out + ((size_t)b * NHEAD + h) * HDIM))[lane] = o;
}

extern "C" void kernel_launch(void* const* d_in, const int* in_sizes, int n_in,
                              void* d_out, int out_size, void* d_ws, size_t ws_size,
                              hipStream_t stream) {
  const float* input  = (const float*)d_in[0];
  const float* kcache = (const float*)d_in[1];
  const float* vcache = (const float*)d_in[2];
  const float* mask   = (const float*)d_in[4];
  const float* Wqkv   = (const float*)d_in[6];
  const float* bqkv   = (const float*)d_in[7];

  float* out   = (float*)d_out;
  float* k_cat = out + (size_t)NB * NHEAD * HDIM;        // 131072
  float* v_cat = k_cat + (size_t)NB * TT * NKV * HDIM;   // +67141632
  float* qkv   = (float*)d_ws;                           // 32*6144 fp32 = 3.1 MB

  qkv_init_k<<<NB * QKVO / 256, 256, 0, stream>>>(qkv, bqkv);
  qkv_gemm_k<<<dim3(QKVO / 64, 8), 256, 0, stream>>>(input, Wqkv, qkv);
  attn_k<<<NB * NKV, 256, 0, stream>>>(kcache, vcache, mask, qkv, out, k_cat, v_cat);
}